// Round 5
// baseline (350.772 us; speedup 1.0000x reference)
//
#include <hip/hip_runtime.h>
#include <math.h>

#define S_TOK 65536
#define H_DIM 768
#define T_TYPES 6
#define K_TOP 3
#define WIN 15
#define NBLK1 512
#define NWAVES (NBLK1 * 4)               // 2048
#define ROWS_PER_WAVE (S_TOK / NWAVES)   // 32
#define POOL_CHUNKS 16
#define BLK_PER_CHUNK (NWAVES / POOL_CHUNKS) // 128 wave-partials per chunk
#define NBLK2 (T_TYPES + POOL_CHUNKS)    // 22

// ---------------------------------------------------------------------------
// top-3 insert with jnp tie-breaking (equal value -> lower index wins)
// ---------------------------------------------------------------------------
__device__ __forceinline__ void top3_insert(float v, int i,
    float& v0, float& v1, float& v2, int& i0, int& i1, int& i2)
{
    if (v > v0 || (v == v0 && i < i0)) {
        v2 = v1; i2 = i1; v1 = v0; i1 = i0; v0 = v; i0 = i;
    } else if (v > v1 || (v == v1 && i < i1)) {
        v2 = v1; i2 = i1; v1 = v; i1 = i;
    } else if (v > v2 || (v == v2 && i < i2)) {
        v2 = v; i2 = i;
    }
}

__device__ __forceinline__ void merge_state(
    float& M, float& se, float& v0, float& v1, float& v2,
    int& i0, int& i1, int& i2,
    float Mb, float seb, float w0, float w1, float w2,
    int j0, int j1, int j2)
{
    const float Mn = fmaxf(M, Mb);
    se = se * expf(M - Mn) + seb * expf(Mb - Mn);
    M = Mn;
    top3_insert(w0, j0, v0, v1, v2, i0, i1, i2);
    top3_insert(w1, j1, v0, v1, v2, i0, i1, i2);
    top3_insert(w2, j2, v0, v1, v2, i0, i1, i2);
}

// ---------------------------------------------------------------------------
// Kernel 1 (R3-best structure): single HBM pass over token_embeds (192 MiB).
// Wave-per-row, next-row prefetch, all 12 outputs per wave (no cross-wave
// row sharing -> no L1/L2 read amplification). Packed-halving butterfly:
// 14 shuffles/row. Designated lanes {0,4,8,16,20,24} hold start types
// (online softmax + top3), {32,36,40,48,52,56} hold end types (stored).
// Pooled partials now per-WAVE, written directly (no LDS, no barrier).
// Block 0 thread 0 also zeroes the k_mid ticket counter.
// ---------------------------------------------------------------------------
__global__ __launch_bounds__(256, 2) void k_scores(
    const float* __restrict__ emb,
    const float* __restrict__ Wstart, const float* __restrict__ bstart,
    const float* __restrict__ Wend,   const float* __restrict__ bend,
    float* __restrict__ endS,         // [T_TYPES][S_TOK]
    float* __restrict__ partials,     // [NWAVES][T_TYPES][8]
    float* __restrict__ pooledPart,   // [NWAVES][H_DIM]
    int* __restrict__ ticket)
{
    if (blockIdx.x == 0 && threadIdx.x == 0) *ticket = 0;

    const int lane = threadIdx.x & 63;
    const int wib  = threadIdx.x >> 6;
    const int wave = blockIdx.x * 4 + wib;

    const bool b5 = (lane & 32) != 0;
    const bool b4 = (lane & 16) != 0;
    const bool b3 = (lane & 8)  != 0;
    const bool b2 = (lane & 4)  != 0;
    const int  sem = (b5 ? 6 : 0) + (b4 ? 3 : 0) + (b3 ? 2 : (b2 ? 1 : 0));
    const bool desig   = ((lane & 3) == 0) && !(b3 && b2);
    const bool isStart = desig && !b5;
    const bool isEnd   = desig && b5;

    float wS[3][4][T_TYPES], wE[3][4][T_TYPES];
#pragma unroll
    for (int j = 0; j < 3; ++j)
#pragma unroll
        for (int c = 0; c < 4; ++c) {
            const int h = 4 * (lane + 64 * j) + c;
#pragma unroll
            for (int t = 0; t < T_TYPES; ++t) {
                wS[j][c][t] = Wstart[h * T_TYPES + t];
                wE[j][c][t] = Wend  [h * T_TYPES + t];
            }
        }

    float myBias = 0.0f;
    if (isStart) myBias = bstart[sem];
    if (isEnd)   myBias = bend[sem - T_TYPES];

    float pool[3][4] = {};

    float M  = -3.402823466e38f, se = 0.0f;
    float v0 = -3.402823466e38f, v1 = v0, v2 = v0;
    int   i0 = -1, i1 = -1, i2 = -1;

    const int r0 = wave * ROWS_PER_WAVE;
    const float4* rowp = (const float4*)emb + (size_t)r0 * (H_DIM / 4);
    float4 c0 = rowp[lane], c1 = rowp[lane + 64], c2 = rowp[lane + 128];

    for (int r = r0; r < r0 + ROWS_PER_WAVE; ++r) {
        const float4* nextp = rowp + ((r + 1 < S_TOK) ? (H_DIM / 4) : 0);
        float4 n0 = nextp[lane], n1 = nextp[lane + 64], n2 = nextp[lane + 128];

        float acc[12];
#pragma unroll
        for (int a = 0; a < 12; ++a) acc[a] = 0.0f;

        const float4 ee[3] = {c0, c1, c2};
#pragma unroll
        for (int j = 0; j < 3; ++j) {
            const float ev[4] = {ee[j].x, ee[j].y, ee[j].z, ee[j].w};
#pragma unroll
            for (int c = 0; c < 4; ++c) {
                const float v = ev[c];
                pool[j][c] += v;
#pragma unroll
                for (int t = 0; t < T_TYPES; ++t) {
                    acc[t]           = fmaf(v, wS[j][c][t], acc[t]);
                    acc[T_TYPES + t] = fmaf(v, wE[j][c][t], acc[T_TYPES + t]);
                }
            }
        }

        // packed-halving butterfly: 14 shuffles
        float na[6];
#pragma unroll
        for (int t = 0; t < 6; ++t) {
            const float snd  = b5 ? acc[t] : acc[t + 6];
            const float keep = b5 ? acc[t + 6] : acc[t];
            na[t] = keep + __shfl_xor(snd, 32, 64);
        }
        float nb[3];
#pragma unroll
        for (int t = 0; t < 3; ++t) {
            const float snd  = b4 ? na[t] : na[t + 3];
            const float keep = b4 ? na[t + 3] : na[t];
            nb[t] = keep + __shfl_xor(snd, 16, 64);
        }
        float nc0, nc1;
        {
            const float keep = b3 ? nb[2] : nb[0];
            nc0 = keep + __shfl_xor(b3 ? nb[0] : nb[2], 8, 64);
            nc1 = nb[1] + __shfl_xor(nb[1], 8, 64);
        }
        float d;
        {
            const float snd  = (b3 || b2) ? nc0 : nc1;
            const float keep = (!b3 && b2) ? nc1 : nc0;
            d = keep + __shfl_xor(snd, 4, 64);
        }
        d += __shfl_xor(d, 2, 64);
        d += __shfl_xor(d, 1, 64);

        const float v = d + myBias;

        if (isStart) {
            if (v > M) {
                se = se * expf(M - v) + 1.0f;
                v2 = v1; i2 = i1; v1 = v0; i1 = i0; v0 = v; i0 = r;
                M = v;
            } else {
                se += expf(v - M);
                if (v > v2 || (v == v2 && r < i2)) {
                    if (v > v1 || (v == v1 && r < i1)) {
                        v2 = v1; i2 = i1; v1 = v; i1 = r;
                    } else { v2 = v; i2 = r; }
                }
            }
        } else if (isEnd) {
            endS[(size_t)(sem - T_TYPES) * S_TOK + r] = v;
        }

        c0 = n0; c1 = n1; c2 = n2; rowp = nextp;
    }

    if (isStart) {
        float* p = partials + ((size_t)wave * T_TYPES + sem) * 8;
        p[0] = M;  p[1] = se; p[2] = v0; p[3] = v1; p[4] = v2;
        p[5] = __int_as_float(i0);
        p[6] = __int_as_float(i1);
        p[7] = __int_as_float(i2);
    }

    // per-wave pooled partial, coalesced float4, no barrier
    float4* pp4 = (float4*)(pooledPart + (size_t)wave * H_DIM);
    pp4[lane]       = make_float4(pool[0][0], pool[0][1], pool[0][2], pool[0][3]);
    pp4[lane + 64]  = make_float4(pool[1][0], pool[1][1], pool[1][2], pool[1][3]);
    pp4[lane + 128] = make_float4(pool[2][0], pool[2][1], pool[2][2], pool[2][3]);
}

// ---------------------------------------------------------------------------
// Kernel 2 (22 blocks x 1024), k_final fused as last-block epilogue:
//   blocks 0..5   : combine 2048 per-wave (M,se,top3) partials of type b
//   blocks 6..21  : pooled chunk reduce (128 wave-partials) + W1 GEMV partial
//   last block    : z-sum -> GELU -> W2 -> sigmoid; softmax top-vals; window
//                   argmax; write all 72 outputs.
// Cross-block handoff uses agent-scope atomic stores/loads (bypass per-XCD
// L2, which is NOT cross-coherent) + __threadfence + ticket counter.
// ---------------------------------------------------------------------------
__global__ __launch_bounds__(1024) void k_mid(
    const float* __restrict__ partials,
    const float* __restrict__ pooledPart,
    const float* __restrict__ W1, const float* __restrict__ b1,
    const float* __restrict__ W2, const float* __restrict__ b2,
    const float* __restrict__ endS,
    float* __restrict__ zpart,          // [POOL_CHUNKS][64]
    float* __restrict__ res,            // [T_TYPES][8]
    int* __restrict__ ticket,
    float* __restrict__ out)
{
    const int b = blockIdx.x;
    const int tid = threadIdx.x;

    __shared__ float pl[H_DIM];
    __shared__ float zred[16][64];
    __shared__ float sm[16][8];
    __shared__ float hdn[64];
    __shared__ float tconf[T_TYPES];
    __shared__ int sLast;

    if (b >= T_TYPES) {
        const int c = b - T_TYPES;
        if (tid < H_DIM) {
            const float* base = pooledPart + (size_t)c * BLK_PER_CHUNK * H_DIM + tid;
            float s[8] = {0, 0, 0, 0, 0, 0, 0, 0};
            for (int i = 0; i < BLK_PER_CHUNK; i += 8) {
#pragma unroll
                for (int u = 0; u < 8; ++u)
                    s[u] += base[(size_t)(i + u) * H_DIM];
            }
            pl[tid] = ((s[0] + s[1]) + (s[2] + s[3])) +
                      ((s[4] + s[5]) + (s[6] + s[7]));
        }
        __syncthreads();
        const int o = tid & 63, seg = tid >> 6;
        float z = 0.0f;
        const int h0 = seg * 48;
        for (int i = 0; i < 48; ++i)
            z = fmaf(pl[h0 + i], W1[(size_t)(h0 + i) * 64 + o], z);
        zred[seg][o] = z;
        __syncthreads();
        if (tid < 64) {
            float s = 0.0f;
#pragma unroll
            for (int g = 0; g < 16; ++g) s += zred[g][tid];
            __hip_atomic_store(&zpart[c * 64 + tid], s,
                               __ATOMIC_RELAXED, __HIP_MEMORY_SCOPE_AGENT);
        }
    } else {
        float M, se, v0, v1, v2; int i0, i1, i2;
        {
            const float* p = partials + ((size_t)tid * T_TYPES + b) * 8;
            M = p[0]; se = p[1]; v0 = p[2]; v1 = p[3]; v2 = p[4];
            i0 = __float_as_int(p[5]); i1 = __float_as_int(p[6]);
            i2 = __float_as_int(p[7]);
        }
        {
            const float* p = partials + ((size_t)(tid + 1024) * T_TYPES + b) * 8;
            merge_state(M, se, v0, v1, v2, i0, i1, i2,
                        p[0], p[1], p[2], p[3], p[4],
                        __float_as_int(p[5]), __float_as_int(p[6]),
                        __float_as_int(p[7]));
        }
#pragma unroll
        for (int msk = 1; msk < 64; msk <<= 1) {
            const float Mb  = __shfl_xor(M,  msk, 64);
            const float seb = __shfl_xor(se, msk, 64);
            const float w0  = __shfl_xor(v0, msk, 64);
            const float w1  = __shfl_xor(v1, msk, 64);
            const float w2  = __shfl_xor(v2, msk, 64);
            const int   j0  = __shfl_xor(i0, msk, 64);
            const int   j1  = __shfl_xor(i1, msk, 64);
            const int   j2  = __shfl_xor(i2, msk, 64);
            merge_state(M, se, v0, v1, v2, i0, i1, i2, Mb, seb, w0, w1, w2,
                        j0, j1, j2);
        }
        if ((tid & 63) == 0) {
            const int w = tid >> 6;
            sm[w][0] = M;  sm[w][1] = se;
            sm[w][2] = v0; sm[w][3] = v1; sm[w][4] = v2;
            sm[w][5] = __int_as_float(i0);
            sm[w][6] = __int_as_float(i1);
            sm[w][7] = __int_as_float(i2);
        }
        __syncthreads();
        if (tid == 0) {
            for (int w = 1; w < 16; ++w) {
                merge_state(M, se, v0, v1, v2, i0, i1, i2,
                            sm[w][0], sm[w][1], sm[w][2], sm[w][3], sm[w][4],
                            __float_as_int(sm[w][5]), __float_as_int(sm[w][6]),
                            __float_as_int(sm[w][7]));
            }
            float* r = res + b * 8;
            __hip_atomic_store(&r[0], v0, __ATOMIC_RELAXED, __HIP_MEMORY_SCOPE_AGENT);
            __hip_atomic_store(&r[1], v1, __ATOMIC_RELAXED, __HIP_MEMORY_SCOPE_AGENT);
            __hip_atomic_store(&r[2], v2, __ATOMIC_RELAXED, __HIP_MEMORY_SCOPE_AGENT);
            __hip_atomic_store(&r[3], __int_as_float(i0), __ATOMIC_RELAXED, __HIP_MEMORY_SCOPE_AGENT);
            __hip_atomic_store(&r[4], __int_as_float(i1), __ATOMIC_RELAXED, __HIP_MEMORY_SCOPE_AGENT);
            __hip_atomic_store(&r[5], __int_as_float(i2), __ATOMIC_RELAXED, __HIP_MEMORY_SCOPE_AGENT);
            __hip_atomic_store(&r[6], M,  __ATOMIC_RELAXED, __HIP_MEMORY_SCOPE_AGENT);
            __hip_atomic_store(&r[7], se, __ATOMIC_RELAXED, __HIP_MEMORY_SCOPE_AGENT);
        }
    }

    // ---- ticket: last block to finish runs the epilogue ----
    __threadfence();
    __syncthreads();
    if (tid == 0) {
        const int old = __hip_atomic_fetch_add(ticket, 1, __ATOMIC_ACQ_REL,
                                               __HIP_MEMORY_SCOPE_AGENT);
        sLast = (old == NBLK2 - 1);
    }
    __syncthreads();
    if (!sLast) return;
    __threadfence();

    if (tid < 64) {
        float zs = 0.0f;
#pragma unroll
        for (int c = 0; c < POOL_CHUNKS; ++c)
            zs += __hip_atomic_load(&zpart[c * 64 + tid],
                                    __ATOMIC_RELAXED, __HIP_MEMORY_SCOPE_AGENT);
        const float z = zs * (1.0f / (float)S_TOK) + b1[tid];
        hdn[tid] = 0.5f * z * (1.0f + erff(z * 0.7071067811865475f));
    }
    __syncthreads();

    if (tid < T_TYPES) {
        float z = b2[tid];
        for (int i = 0; i < 64; ++i) z = fmaf(hdn[i], W2[i * T_TYPES + tid], z);
        tconf[tid] = 1.0f / (1.0f + expf(-z));
    }
    __syncthreads();

    if (tid < T_TYPES * K_TOP) {
        const int t = tid / K_TOP;
        const int k = tid % K_TOP;
        const float vraw = __hip_atomic_load(&res[t * 8 + k],
                                __ATOMIC_RELAXED, __HIP_MEMORY_SCOPE_AGENT);
        const int idx = __float_as_int(__hip_atomic_load(&res[t * 8 + 3 + k],
                                __ATOMIC_RELAXED, __HIP_MEMORY_SCOPE_AGENT));
        const float M  = __hip_atomic_load(&res[t * 8 + 6],
                                __ATOMIC_RELAXED, __HIP_MEMORY_SCOPE_AGENT);
        const float SE = __hip_atomic_load(&res[t * 8 + 7],
                                __ATOMIC_RELAXED, __HIP_MEMORY_SCOPE_AGENT);
        const float prob = expf(vraw - M) / SE;

        const float* ecol = endS + (size_t)t * S_TOK;
        float best = -3.402823466e38f;
        int   boff = 0;
#pragma unroll
        for (int w = 0; w < WIN; ++w) {
            const int pos = idx + w;
            if (pos < S_TOK) {
                const float ev = ecol[pos];
                if (ev > best) { best = ev; boff = w; }
            }
        }
        const float tc = tconf[t];
        const bool valid = (tc >= 0.3f) && (prob >= 0.15f);
        out[tid]      = valid ? prob * tc : 0.0f;
        out[18 + tid] = (float)idx;
        out[36 + tid] = (float)(idx + boff + 1);
        out[54 + tid] = valid ? 1.0f : 0.0f;
    }
}

extern "C" void kernel_launch(void* const* d_in, const int* in_sizes, int n_in,
                              void* d_out, int out_size, void* d_ws, size_t ws_size,
                              hipStream_t stream)
{
    const float* emb    = (const float*)d_in[0];
    const float* Wstart = (const float*)d_in[1];
    const float* bstart = (const float*)d_in[2];
    const float* Wend   = (const float*)d_in[3];
    const float* bend   = (const float*)d_in[4];
    const float* W1     = (const float*)d_in[5];
    const float* b1     = (const float*)d_in[6];
    const float* W2     = (const float*)d_in[7];
    const float* b2     = (const float*)d_in[8];
    float* out = (float*)d_out;

    // workspace layout (floats)
    float* ws       = (float*)d_ws;
    float* endS     = ws;                                          // 6*65536
    float* partials = endS + (size_t)T_TYPES * S_TOK;              // 2048*6*8
    float* pp       = partials + (size_t)NWAVES * T_TYPES * 8;     // 2048*768
    float* zpart    = pp + (size_t)NWAVES * H_DIM;                 // 16*64
    float* res      = zpart + (size_t)POOL_CHUNKS * 64;            // 6*8
    int*   ticket   = (int*)(res + T_TYPES * 8);

    k_scores<<<NBLK1, 256, 0, stream>>>(emb, Wstart, bstart, Wend, bend,
                                        endS, partials, pp, ticket);
    k_mid<<<NBLK2, 1024, 0, stream>>>(partials, pp, W1, b1, W2, b2,
                                      endS, zpart, res, ticket, out);
}